// Round 2
// baseline (802.118 us; speedup 1.0000x reference)
//
#include <hip/hip_runtime.h>
#include <math.h>
#include <stdint.h>

// MultiResEncoding: Instant-NGP style 2D multires hash grid.
// N = 2^21 points, 16 levels, 2 features/level, table 2^19 entries (f32x2).
// Level 0 dense 16x16 grid; levels 1..15 hashed with primes (1, 2654435761).
//
// Parallelization: 8 threads per point. Thread (n, j) computes levels 2j and
// 2j+1 and writes one float4 at out[n*32 + 4j] -> fully coalesced wave
// stores, no LDS transpose. Gathers are per-(point,level) regardless of
// decomposition, so no duplicated table traffic.
//
// R1 fix: level 2j uses hash_tables[2j-1] (was wrongly 2j-2).

#define TMASK  ((1u << 19) - 1)
#define PRIME2 2654435761u

typedef float vfloat4 __attribute__((ext_vector_type(4)));

__device__ __forceinline__ float2 bilerp_hash(const float2* __restrict__ t,
                                              float x, float y, int rm1) {
    float rf = (float)rm1;
    float fx = x * rf, fy = y * rf;
    float x0f = floorf(fx), y0f = floorf(fy);
    float wx = fx - x0f, wy = fy - y0f;
    int ix0 = (int)x0f; ix0 = ix0 < 0 ? 0 : (ix0 > rm1 ? rm1 : ix0);
    int iy0 = (int)y0f; iy0 = iy0 < 0 ? 0 : (iy0 > rm1 ? rm1 : iy0);
    int ix1 = ix0 + 1 > rm1 ? rm1 : ix0 + 1;
    int iy1 = iy0 + 1 > rm1 ? rm1 : iy0 + 1;
    // PRIMES[0] == 1, so h = ix ^ (iy * PRIME2)
    unsigned hy0 = (unsigned)iy0 * PRIME2;
    unsigned hy1 = (unsigned)iy1 * PRIME2;
    float2 f00 = t[((unsigned)ix0 ^ hy0) & TMASK];
    float2 f01 = t[((unsigned)ix0 ^ hy1) & TMASK];
    float2 f10 = t[((unsigned)ix1 ^ hy0) & TMASK];
    float2 f11 = t[((unsigned)ix1 ^ hy1) & TMASK];
    float omx = 1.0f - wx, omy = 1.0f - wy;
    float w00 = omx * omy, w01 = omx * wy, w10 = wx * omy, w11 = wx * wy;
    return make_float2(f00.x * w00 + f01.x * w01 + f10.x * w10 + f11.x * w11,
                       f00.y * w00 + f01.y * w01 + f10.y * w10 + f11.y * w11);
}

__device__ __forceinline__ float2 bilerp_dense(const float2* __restrict__ t,
                                               float x, float y) {
    const int rm1 = 15;  // level-0 res is exactly 16 (b^0 == 1)
    float rf = (float)rm1;
    float fx = x * rf, fy = y * rf;
    float x0f = floorf(fx), y0f = floorf(fy);
    float wx = fx - x0f, wy = fy - y0f;
    int ix0 = (int)x0f; ix0 = ix0 < 0 ? 0 : (ix0 > rm1 ? rm1 : ix0);
    int iy0 = (int)y0f; iy0 = iy0 < 0 ? 0 : (iy0 > rm1 ? rm1 : iy0);
    int ix1 = ix0 + 1 > rm1 ? rm1 : ix0 + 1;
    int iy1 = iy0 + 1 > rm1 ? rm1 : iy0 + 1;
    float2 f00 = t[ix0 * 16 + iy0];
    float2 f01 = t[ix0 * 16 + iy1];
    float2 f10 = t[ix1 * 16 + iy0];
    float2 f11 = t[ix1 * 16 + iy1];
    float omx = 1.0f - wx, omy = 1.0f - wy;
    float w00 = omx * omy, w01 = omx * wy, w10 = wx * omy, w11 = wx * wy;
    return make_float2(f00.x * w00 + f01.x * w01 + f10.x * w10 + f11.x * w11,
                       f00.y * w00 + f01.y * w01 + f10.y * w10 + f11.y * w11);
}

__global__ __launch_bounds__(256) void mre_kernel(
    const float* __restrict__ cxp, const float* __restrict__ cyp,
    const float2* __restrict__ dense, const float2* __restrict__ hasht,
    float4* __restrict__ out, uint4 wa, uint4 wb)
{
    unsigned gid = blockIdx.x * 256u + threadIdx.x;
    unsigned n = gid >> 3;
    unsigned j = gid & 7u;

    float x = cxp[n];   // 8-lane broadcast, coalesced across the wave
    float y = cyp[n];

    // select packed (rm1[2j] | rm1[2j+1]<<16) via cndmask chain (no scratch)
    unsigned w = j < 4u ? (j < 2u ? (j == 0u ? wa.x : wa.y)
                                  : (j == 2u ? wa.z : wa.w))
                        : (j < 6u ? (j == 4u ? wb.x : wb.y)
                                  : (j == 6u ? wb.z : wb.w));
    int rm1a = (int)(w & 0xFFFFu);
    int rm1b = (int)(w >> 16);

    float2 fa;
    if (j == 0u) {
        fa = bilerp_dense(dense, x, y);
    } else {
        // level l0 = 2j (>=2 here) -> hash table index 2j-1
        fa = bilerp_hash(hasht + (size_t)(2u * j - 1u) * 524288u, x, y, rm1a);
    }
    // level l1 = 2j+1 -> hash table index 2j
    float2 fb = bilerp_hash(hasht + (size_t)(2u * j) * 524288u, x, y, rm1b);

    vfloat4 o = { fa.x, fa.y, fb.x, fb.y };
    // non-temporal: keep the 256 MB output stream from evicting tables in L2
    __builtin_nontemporal_store(o, (vfloat4*)&out[(size_t)n * 8u + j]);
}

extern "C" void kernel_launch(void* const* d_in, const int* in_sizes, int n_in,
                              void* d_out, int out_size, void* d_ws, size_t ws_size,
                              hipStream_t stream)
{
    const float*  cx    = (const float*)d_in[0];
    const float*  cy    = (const float*)d_in[1];
    const float2* dense = (const float2*)d_in[2];
    const float2* hasht = (const float2*)d_in[3];
    float4*       out   = (float4*)d_out;
    const int N = in_sizes[0];

    // Replicate numpy's RES_LEVELS: b = exp((log(2048)-log(16))/15),
    // r_l = floor(16 * b**l), in IEEE double via the same libm op sequence.
    // NOTE: l=15 is 2048 +/- ~1e-12 of the floor boundary — if this round
    // fails at ~2e-4 absmax with everything else audited, flip r[15].
    int r[16];
    for (int l = 0; l < 16; ++l) {
        double b = exp((log(2048.0) - log(16.0)) / 15.0);
        r[l] = (int)floor(16.0 * pow(b, (double)l));
    }
    unsigned pw[8];
    for (int k = 0; k < 8; ++k)
        pw[k] = (unsigned)(r[2 * k] - 1) | ((unsigned)(r[2 * k + 1] - 1) << 16);
    uint4 wa = make_uint4(pw[0], pw[1], pw[2], pw[3]);
    uint4 wb = make_uint4(pw[4], pw[5], pw[6], pw[7]);

    long long total = (long long)N * 8;
    int blocks = (int)((total + 255) / 256);
    hipLaunchKernelGGL(mre_kernel, dim3(blocks), dim3(256), 0, stream,
                       cx, cy, dense, hasht, out, wa, wb);
}

// Round 3
// 801.164 us; speedup vs baseline: 1.0012x; 1.0012x over previous
//
#include <hip/hip_runtime.h>
#include <math.h>
#include <stdint.h>

// MultiResEncoding: Instant-NGP 2D multires hash grid. N=2^21, 16 levels,
// F=2, table 2^19 x float2. Level 0 dense 16x16; levels 1..15 hashed.
//
// R2: 4 threads/point, 4 levels/thread. All 16 gather offsets computed
// up-front, all 16 global_load_dwordx2 issued before any FMA -> ~16
// outstanding loads/thread (was ~2 at VGPR=16) to hide L2/L3 gather
// latency. Dense level-0 table (2 KB) staged in LDS. 32-bit byte offsets
// into the 60 MB hash-table block (1 VGPR per address).

#define TMASK  ((1u << 19) - 1)
#define PRIME2 2654435761u

typedef float vfloat4 __attribute__((ext_vector_type(4)));

__global__ __launch_bounds__(256) void mre_kernel(
    const float* __restrict__ cxp, const float* __restrict__ cyp,
    const float2* __restrict__ dense, const float2* __restrict__ hasht,
    float4* __restrict__ out, uint4 wa, uint4 wb)
{
    __shared__ float2 sdense[256];            // 16x16 level-0 grid, 2 KB
    sdense[threadIdx.x] = dense[threadIdx.x];
    __syncthreads();

    unsigned gid = blockIdx.x * 256u + threadIdx.x;
    unsigned n = gid >> 2;
    unsigned j = gid & 3u;                    // levels 4j .. 4j+3

    float x = cxp[n];                         // 4-lane broadcast
    float y = cyp[n];

    // pw[k] packs (r[2k]-1) | (r[2k+1]-1)<<16. Thread j needs pw[2j], pw[2j+1].
    unsigned w0 = j < 2u ? (j == 0u ? wa.x : wa.z) : (j == 2u ? wb.x : wb.z);
    unsigned w1 = j < 2u ? (j == 0u ? wa.y : wa.w) : (j == 2u ? wb.y : wb.w);
    int rm1[4] = { (int)(w0 & 0xffffu), (int)(w0 >> 16),
                   (int)(w1 & 0xffffu), (int)(w1 >> 16) };

    unsigned o00[4], o01[4], o10[4], o11[4];  // byte offsets into hasht
    float wx[4], wy[4];
    unsigned d00 = 0, d01 = 0, d10 = 0, d11 = 0;  // LDS idx for level 0
    const bool lvl0 = (j == 0u);

    #pragma unroll
    for (int k = 0; k < 4; ++k) {
        int r = rm1[k];
        float rf = (float)r;
        float fx = x * rf, fy = y * rf;
        float x0f = floorf(fx), y0f = floorf(fy);
        wx[k] = fx - x0f;  wy[k] = fy - y0f;
        int ix0 = (int)x0f; ix0 = ix0 < 0 ? 0 : (ix0 > r ? r : ix0);
        int iy0 = (int)y0f; iy0 = iy0 < 0 ? 0 : (iy0 > r ? r : iy0);
        int ix1 = ix0 + 1 > r ? r : ix0 + 1;
        int iy1 = iy0 + 1 > r ? r : iy0 + 1;
        if (k == 0) { d00 = ix0 * 16 + iy0; d01 = ix0 * 16 + iy1;
                      d10 = ix1 * 16 + iy0; d11 = ix1 * 16 + iy1; }
        // level l = 4j+k -> hash table l-1; clamp the unused (j=0,k=0) slot
        unsigned ti = j * 4u + (unsigned)k;
        ti = ti == 0u ? 0u : ti - 1u;
        unsigned tb = ti << 22;               // ti * 2^19 entries * 8 B
        unsigned hy0 = (unsigned)iy0 * PRIME2;
        unsigned hy1 = (unsigned)iy1 * PRIME2;
        o00[k] = tb + ((((unsigned)ix0 ^ hy0) & TMASK) << 3);
        o01[k] = tb + ((((unsigned)ix0 ^ hy1) & TMASK) << 3);
        o10[k] = tb + ((((unsigned)ix1 ^ hy0) & TMASK) << 3);
        o11[k] = tb + ((((unsigned)ix1 ^ hy1) & TMASK) << 3);
    }

    const char* hb = (const char*)hasht;
    // Issue the 12 unconditional gathers (k=1..3) first, then the masked
    // level-4j group, so everything is in flight before the first use.
    float2 f00[4], f01[4], f10[4], f11[4];
    #pragma unroll
    for (int k = 1; k < 4; ++k) {
        f00[k] = *(const float2*)(hb + o00[k]);
        f01[k] = *(const float2*)(hb + o01[k]);
        f10[k] = *(const float2*)(hb + o10[k]);
        f11[k] = *(const float2*)(hb + o11[k]);
    }
    if (lvl0) {
        f00[0] = sdense[d00]; f01[0] = sdense[d01];
        f10[0] = sdense[d10]; f11[0] = sdense[d11];
    } else {
        f00[0] = *(const float2*)(hb + o00[0]);
        f01[0] = *(const float2*)(hb + o01[0]);
        f10[0] = *(const float2*)(hb + o10[0]);
        f11[0] = *(const float2*)(hb + o11[0]);
    }

    float2 acc[4];
    #pragma unroll
    for (int k = 0; k < 4; ++k) {
        float omx = 1.0f - wx[k], omy = 1.0f - wy[k];
        float w00 = omx * omy, w01 = omx * wy[k];
        float w10 = wx[k] * omy, w11 = wx[k] * wy[k];
        acc[k].x = f00[k].x * w00 + f01[k].x * w01 + f10[k].x * w10 + f11[k].x * w11;
        acc[k].y = f00[k].y * w00 + f01[k].y * w01 + f10[k].y * w10 + f11[k].y * w11;
    }

    vfloat4 o0 = { acc[0].x, acc[0].y, acc[1].x, acc[1].y };
    vfloat4 o1 = { acc[2].x, acc[2].y, acc[3].x, acc[3].y };
    size_t base = (size_t)n * 8u + 2u * j;
    __builtin_nontemporal_store(o0, (vfloat4*)&out[base]);
    __builtin_nontemporal_store(o1, (vfloat4*)&out[base + 1]);
}

extern "C" void kernel_launch(void* const* d_in, const int* in_sizes, int n_in,
                              void* d_out, int out_size, void* d_ws, size_t ws_size,
                              hipStream_t stream)
{
    const float*  cx    = (const float*)d_in[0];
    const float*  cy    = (const float*)d_in[1];
    const float2* dense = (const float2*)d_in[2];
    const float2* hasht = (const float2*)d_in[3];
    float4*       out   = (float4*)d_out;
    const int N = in_sizes[0];

    // numpy RES_LEVELS replica (host glibc doubles — verified passing in R2)
    int r[16];
    for (int l = 0; l < 16; ++l) {
        double b = exp((log(2048.0) - log(16.0)) / 15.0);
        r[l] = (int)floor(16.0 * pow(b, (double)l));
    }
    unsigned pw[8];
    for (int k = 0; k < 8; ++k)
        pw[k] = (unsigned)(r[2 * k] - 1) | ((unsigned)(r[2 * k + 1] - 1) << 16);
    uint4 wa = make_uint4(pw[0], pw[1], pw[2], pw[3]);
    uint4 wb = make_uint4(pw[4], pw[5], pw[6], pw[7]);

    long long total = (long long)N * 4;
    int blocks = (int)((total + 255) / 256);
    hipLaunchKernelGGL(mre_kernel, dim3(blocks), dim3(256), 0, stream,
                       cx, cy, dense, hasht, out, wa, wb);
}